// Round 2
// baseline (1447.708 us; speedup 1.0000x reference)
//
#include <hip/hip_runtime.h>

#define N_NODES 100000
#define N_EDGES 3200000
#define DDIM 256
#define NB 1563          // ceil(100000/64) buckets of 64 dst nodes
#define BIN_BLK 256      // blocks for hist/bin passes; 3.2M/256 = 12500 edges/block
#define CHUNK (N_EDGES / BIN_BLK)
#define PDIM 16          // dims per panel
#define NPANEL (DDIM / PDIM)   // 16 panels; panel slab = 100000*16*2B = 3.2MB -> L2-resident
#define PSTRIDE ((size_t)N_NODES * PDIM)

typedef short s16x8 __attribute__((ext_vector_type(8)));
typedef float f32x4 __attribute__((ext_vector_type(4)));

__device__ __forceinline__ unsigned short f32_to_bf16(float f) {
    union { float f; unsigned int u; } c; c.f = f;
    unsigned int u = c.u;
    unsigned int r = u + 0x7fffu + ((u >> 16) & 1u);  // RNE
    return (unsigned short)(r >> 16);
}
__device__ __forceinline__ float bf16s(unsigned short h) {
    union { unsigned int u; float f; } c; c.u = ((unsigned int)h) << 16;
    return c.f;
}

// ---------------- W -> Wt (bf16, transposed to [n][k]) ----------------
__global__ __launch_bounds__(256) void prep_w(const float* __restrict__ W,
                                              unsigned short* __restrict__ Wt) {
    __shared__ float tile[32][33];
    const int tx = threadIdx.x & 31;
    const int ty = threadIdx.x >> 5;
    const int n0 = blockIdx.x * 32;
    const int k0 = blockIdx.y * 32;
    for (int i = 0; i < 32; i += 8)
        tile[ty + i][tx] = W[(size_t)(k0 + ty + i) * DDIM + n0 + tx];
    __syncthreads();
    for (int i = 0; i < 32; i += 8)
        Wt[(size_t)(n0 + ty + i) * DDIM + k0 + tx] = f32_to_bf16(tile[tx][ty + i]);
}

// -------- MFMA bf16 GEMM: xb[p][node][16] = bf16(A @ W), panel-major --------
__global__ __launch_bounds__(256) void gemm_mfma(const float* __restrict__ A,
                                                 const unsigned short* __restrict__ Wt,
                                                 unsigned short* __restrict__ Xb) {
    __shared__ unsigned short As[64][DDIM + 8];
    const int tid = threadIdx.x;
    const int rowBase = blockIdx.x * 64;

#pragma unroll
    for (int p = 0; p < 16; ++p) {
        const int flat = p * 256 + tid;
        const int row = flat >> 6;
        const int k4 = (flat & 63) * 4;
        const int gr = rowBase + row;
        float4 v = make_float4(0.f, 0.f, 0.f, 0.f);
        if (gr < N_NODES) v = *(const float4*)&A[(size_t)gr * DDIM + k4];
        ushort4 h;
        h.x = f32_to_bf16(v.x); h.y = f32_to_bf16(v.y);
        h.z = f32_to_bf16(v.z); h.w = f32_to_bf16(v.w);
        *(ushort4*)&As[row][k4] = h;
    }
    __syncthreads();

    const int wave = tid >> 6;
    const int lane = tid & 63;
    const int lrow = lane & 15;
    const int quad = lane >> 4;
    const int cb = wave * 64;

    f32x4 acc[4][4] = {};

#pragma unroll
    for (int ks = 0; ks < 8; ++ks) {
        const int k0 = ks * 32 + quad * 8;
        s16x8 a[4], b[4];
#pragma unroll
        for (int ri = 0; ri < 4; ++ri)
            a[ri] = *(const s16x8*)&As[ri * 16 + lrow][k0];
#pragma unroll
        for (int ci = 0; ci < 4; ++ci)
            b[ci] = *(const s16x8*)&Wt[(size_t)(cb + ci * 16 + lrow) * DDIM + k0];
#pragma unroll
        for (int ri = 0; ri < 4; ++ri)
#pragma unroll
            for (int ci = 0; ci < 4; ++ci)
                acc[ri][ci] = __builtin_amdgcn_mfma_f32_16x16x32_bf16(a[ri], b[ci], acc[ri][ci], 0, 0, 0);
    }

    // store panel-major: column cb+ci*16+lrow -> panel (wave*4+ci), dim lrow
#pragma unroll
    for (int ri = 0; ri < 4; ++ri) {
        const int r0 = rowBase + ri * 16 + quad * 4;
#pragma unroll
        for (int rr = 0; rr < 4; ++rr) {
            const int row = r0 + rr;
            if (row < N_NODES) {
#pragma unroll
                for (int ci = 0; ci < 4; ++ci)
                    Xb[(size_t)(wave * 4 + ci) * PSTRIDE + (size_t)row * PDIM + lrow] =
                        f32_to_bf16(acc[ri][ci][rr]);
            }
        }
    }
}

// ---------------- two-level CSR build ----------------
__global__ __launch_bounds__(256) void zero_small(int* __restrict__ p, int n) {
    int i = blockIdx.x * 256 + threadIdx.x;
    if (i < n) p[i] = 0;
}

// K1: coarse histogram over NB buckets (bucket = dst>>6)
__global__ __launch_bounds__(256) void hist_coarse(const int* __restrict__ edst,
                                                   int* __restrict__ gcounts) {
    __shared__ int h[NB];
    const int tid = threadIdx.x;
    for (int i = tid; i < NB; i += 256) h[i] = 0;
    __syncthreads();
    const int lo = blockIdx.x * CHUNK;
    const int hi = lo + CHUNK;
    for (int e = lo + tid; e < hi; e += 256) atomicAdd(&h[edst[e] >> 6], 1);
    __syncthreads();
    for (int i = tid; i < NB; i += 256)
        if (h[i]) atomicAdd(&gcounts[i], h[i]);
}

// K2: scan NB bucket counts -> bbase[NB+1], bcursor copy; also off[N_NODES]=E
__global__ __launch_bounds__(256) void scan_coarse(const int* __restrict__ gcounts,
                                                   int* __restrict__ bbase,
                                                   int* __restrict__ bcursor,
                                                   int* __restrict__ off) {
    __shared__ int part[256];
    const int t = threadIdx.x;
    const int chunk = (NB + 255) / 256;  // 7
    const int lo = t * chunk;
    const int hi = min(lo + chunk, NB);
    int s = 0;
    for (int i = lo; i < hi; ++i) s += gcounts[i];
    part[t] = s;
    __syncthreads();
    for (int d = 1; d < 256; d <<= 1) {
        int a = (t >= d) ? part[t - d] : 0;
        __syncthreads();
        part[t] += a;
        __syncthreads();
    }
    int run = part[t] - s;
    for (int i = lo; i < hi; ++i) {
        bbase[i] = run;
        bcursor[i] = run;
        run += gcounts[i];
    }
    if (t == 255) {
        bbase[NB] = run;
        off[N_NODES] = run;  // == N_EDGES
    }
}

// K3: bin edges into coarse buckets
__global__ __launch_bounds__(256) void bin_coarse(const int* __restrict__ esrc,
                                                  const int* __restrict__ edst,
                                                  const float* __restrict__ evals,
                                                  int* __restrict__ bcursor,
                                                  int2* __restrict__ tmp) {
    __shared__ int h[NB];
    __shared__ int sb[NB];
    const int tid = threadIdx.x;
    for (int i = tid; i < NB; i += 256) h[i] = 0;
    __syncthreads();
    const int lo = blockIdx.x * CHUNK;
    const int hi = lo + CHUNK;
    for (int e = lo + tid; e < hi; e += 256) atomicAdd(&h[edst[e] >> 6], 1);
    __syncthreads();
    for (int i = tid; i < NB; i += 256)
        sb[i] = h[i] ? atomicAdd(&bcursor[i], h[i]) : 0;
    __syncthreads();
    for (int e = lo + tid; e < hi; e += 256) {
        const int d = edst[e];
        const int b = d >> 6;
        const int p = atomicAdd(&sb[b], 1);  // LDS atomic; sb now acts as cursor
        tmp[p] = make_int2(esrc[e] | ((d & 63) << 17), __float_as_int(evals[e]));
    }
}

// K4: refine within bucket: exact per-node CSR offsets + scatter inside a
// ~16KB window. One workgroup per bucket. Output reused 16x by panel gather.
__global__ __launch_bounds__(256) void refine(const int2* __restrict__ tmp,
                                              const int* __restrict__ bbase,
                                              int* __restrict__ off,
                                              int2* __restrict__ srcval) {
    __shared__ int nh[64];
    __shared__ int nb[64];
    const int b = blockIdx.x;
    const int tid = threadIdx.x;
    const int base = bbase[b];
    const int cnt = bbase[b + 1] - base;
    const int n0 = b * 64;
    const int nn = min(64, N_NODES - n0);
    if (tid < 64) nh[tid] = 0;
    __syncthreads();
    for (int i = tid; i < cnt; i += 256)
        atomicAdd(&nh[tmp[base + i].x >> 17], 1);
    __syncthreads();
    if (tid == 0) {
        int run = 0;
        for (int i = 0; i < 64; ++i) { nb[i] = run; run += nh[i]; }
    }
    __syncthreads();
    if (tid < nn) off[n0 + tid] = base + nb[tid];
    __syncthreads();  // off-write reads nb before pass-2 mutates it
    for (int i = tid; i < cnt; i += 256) {
        const int2 r = tmp[base + i];
        const int dl = r.x >> 17;
        const int p = atomicAdd(&nb[dl], 1);
        srcval[base + p] = make_int2(r.x & 0x1FFFF, r.y);
    }
}

// ---------------- panelized SpMM gather + fused ReLU ----------------
// Block = (panel p, bucket b). Panel slab xb[p] is 3.2MB -> L2-resident while
// panel-major dispatch keeps concurrent blocks on the same panel. Records
// (srcval) are re-streamed per panel with nontemporal loads so the stream
// doesn't evict the panel. lane = edge_sub(0..3) x dim(0..15); 8 edges in
// flight per wave; 2-step shfl_xor reduce per dst; no LDS at all.
__global__ __launch_bounds__(256) void spmm_panel(const unsigned short* __restrict__ xb,
                                                  const int* __restrict__ off,
                                                  const int2* __restrict__ srcval,
                                                  float* __restrict__ out) {
    const int bp = blockIdx.x;
    const int p  = bp / NB;          // panel index (panel-major)
    const int b  = bp - p * NB;      // bucket
    const int n0 = b << 6;
    const int wave = threadIdx.x >> 6;
    const int lane = threadIdx.x & 63;
    const int dim  = lane & 15;
    const int es   = lane >> 4;      // edge sub-slot 0..3

    const unsigned short* xp = xb + (size_t)p * PSTRIDE + dim;  // + src*PDIM

    for (int dd = 0; dd < 16; ++dd) {
        const int node = n0 + (wave << 4) + dd;
        if (node >= N_NODES) break;  // wave-uniform
        int j = off[node];
        const int je = off[node + 1];
        float acc0 = 0.f, acc1 = 0.f;
        for (; j + 8 <= je; j += 8) {
            const long long q0 = __builtin_nontemporal_load((const long long*)(srcval + j + es));
            const long long q1 = __builtin_nontemporal_load((const long long*)(srcval + j + 4 + es));
            const int s0 = (int)(q0 & 0x1FFFF);
            const int s1 = (int)(q1 & 0x1FFFF);
            const float v0 = __int_as_float((int)(q0 >> 32));
            const float v1 = __int_as_float((int)(q1 >> 32));
            const unsigned short x0 = xp[(size_t)s0 * PDIM];
            const unsigned short x1 = xp[(size_t)s1 * PDIM];
            acc0 += v0 * bf16s(x0);
            acc1 += v1 * bf16s(x1);
        }
        for (; j < je; j += 4) {
            int s = 0; float v = 0.f;
            if (j + es < je) {
                const long long q = __builtin_nontemporal_load((const long long*)(srcval + j + es));
                s = (int)(q & 0x1FFFF);
                v = __int_as_float((int)(q >> 32));
            }
            const unsigned short x = xp[(size_t)s * PDIM];
            acc0 += v * bf16s(x);
        }
        float acc = acc0 + acc1;
        acc += __shfl_xor(acc, 16);
        acc += __shfl_xor(acc, 32);
        if (es == 0)
            out[(size_t)node * DDIM + p * PDIM + dim] = fmaxf(acc, 0.f);
    }
}

extern "C" void kernel_launch(void* const* d_in, const int* in_sizes, int n_in,
                              void* d_out, int out_size, void* d_ws, size_t ws_size,
                              hipStream_t stream) {
    const float* inputs = (const float*)d_in[0];
    const float* weight = (const float*)d_in[1];
    const int* esrc     = (const int*)d_in[2];
    const int* edst     = (const int*)d_in[3];
    const float* evals  = (const float*)d_in[4];
    float* out = (float*)d_out;

    // workspace layout (16B alignment maintained)
    unsigned short* xb = (unsigned short*)d_ws;                  // 25.6M ushort (panel-major)
    unsigned short* Wt = xb + (size_t)N_NODES * DDIM;            // 65536 ushort
    int* off     = (int*)(Wt + DDIM * DDIM);                     // 100001
    int* gcounts = off + N_NODES + 1;                            // NB
    int* bbase   = gcounts + NB;                                 // NB+1
    int* bcursor = bbase + NB + 1;                               // NB
    uintptr_t a  = ((uintptr_t)(bcursor + NB) + 15) & ~(uintptr_t)15;
    int2* tmp    = (int2*)a;                                     // 3.2M int2
    int2* srcval = tmp + N_EDGES;                                // 3.2M int2

    // 1) Wt = bf16(W^T)
    prep_w<<<dim3(8, 8), 256, 0, stream>>>(weight, Wt);

    // 2) xb = bf16(inputs @ W), panel-major layout
    gemm_mfma<<<(N_NODES + 63) / 64, 256, 0, stream>>>(inputs, Wt, xb);

    // 3) two-level CSR build (sort once, reuse 16x)
    zero_small<<<(NB + 255) / 256, 256, 0, stream>>>(gcounts, NB);
    hist_coarse<<<BIN_BLK, 256, 0, stream>>>(edst, gcounts);
    scan_coarse<<<1, 256, 0, stream>>>(gcounts, bbase, bcursor, off);
    bin_coarse<<<BIN_BLK, 256, 0, stream>>>(esrc, edst, evals, bcursor, tmp);
    refine<<<NB, 256, 0, stream>>>(tmp, bbase, off, srcval);

    // 4) panelized gather-accumulate + ReLU; panel-major dispatch for L2 reuse
    spmm_panel<<<NB * NPANEL, 256, 0, stream>>>(xb, off, srcval, out);
}

// Round 4
// 659.822 us; speedup vs baseline: 2.1941x; 2.1941x over previous
//
#include <hip/hip_runtime.h>

#define N_NODES 100000
#define N_EDGES 3200000
#define DDIM 256
#define NB 1563          // ceil(100000/64) buckets of 64 dst nodes
#define BIN_BLK 256      // blocks for hist/bin passes; 3.2M/256 = 12500 edges/block
#define CHUNK (N_EDGES / BIN_BLK)

typedef short s16x8 __attribute__((ext_vector_type(8)));
typedef float f32x4 __attribute__((ext_vector_type(4)));

__device__ __forceinline__ unsigned short f32_to_bf16(float f) {
    union { float f; unsigned int u; } c; c.f = f;
    unsigned int u = c.u;
    unsigned int r = u + 0x7fffu + ((u >> 16) & 1u);  // RNE
    return (unsigned short)(r >> 16);
}
__device__ __forceinline__ float bf16_to_f32(unsigned short h) {
    union { unsigned int u; float f; } c; c.u = ((unsigned int)h) << 16;
    return c.f;
}

// ---------------- W -> Wt (bf16, transposed to [n][k]) ----------------
__global__ __launch_bounds__(256) void prep_w(const float* __restrict__ W,
                                              unsigned short* __restrict__ Wt) {
    __shared__ float tile[32][33];
    const int tx = threadIdx.x & 31;
    const int ty = threadIdx.x >> 5;
    const int n0 = blockIdx.x * 32;
    const int k0 = blockIdx.y * 32;
    for (int i = 0; i < 32; i += 8)
        tile[ty + i][tx] = W[(size_t)(k0 + ty + i) * DDIM + n0 + tx];
    __syncthreads();
    for (int i = 0; i < 32; i += 8)
        Wt[(size_t)(n0 + ty + i) * DDIM + k0 + tx] = f32_to_bf16(tile[tx][ty + i]);
}

// ---------------- MFMA bf16 GEMM: Xb[N,256] = bf16(A) @ bf16(W) ----------------
__global__ __launch_bounds__(256) void gemm_mfma(const float* __restrict__ A,
                                                 const unsigned short* __restrict__ Wt,
                                                 unsigned short* __restrict__ Xb) {
    __shared__ unsigned short As[64][DDIM + 8];
    const int tid = threadIdx.x;
    const int rowBase = blockIdx.x * 64;

#pragma unroll
    for (int p = 0; p < 16; ++p) {
        const int flat = p * 256 + tid;
        const int row = flat >> 6;
        const int k4 = (flat & 63) * 4;
        const int gr = rowBase + row;
        float4 v = make_float4(0.f, 0.f, 0.f, 0.f);
        if (gr < N_NODES) v = *(const float4*)&A[(size_t)gr * DDIM + k4];
        ushort4 h;
        h.x = f32_to_bf16(v.x); h.y = f32_to_bf16(v.y);
        h.z = f32_to_bf16(v.z); h.w = f32_to_bf16(v.w);
        *(ushort4*)&As[row][k4] = h;
    }
    __syncthreads();

    const int wave = tid >> 6;
    const int lane = tid & 63;
    const int lrow = lane & 15;
    const int quad = lane >> 4;
    const int cb = wave * 64;

    f32x4 acc[4][4] = {};

#pragma unroll
    for (int ks = 0; ks < 8; ++ks) {
        const int k0 = ks * 32 + quad * 8;
        s16x8 a[4], b[4];
#pragma unroll
        for (int ri = 0; ri < 4; ++ri)
            a[ri] = *(const s16x8*)&As[ri * 16 + lrow][k0];
#pragma unroll
        for (int ci = 0; ci < 4; ++ci)
            b[ci] = *(const s16x8*)&Wt[(size_t)(cb + ci * 16 + lrow) * DDIM + k0];
#pragma unroll
        for (int ri = 0; ri < 4; ++ri)
#pragma unroll
            for (int ci = 0; ci < 4; ++ci)
                acc[ri][ci] = __builtin_amdgcn_mfma_f32_16x16x32_bf16(a[ri], b[ci], acc[ri][ci], 0, 0, 0);
    }

    // xb stores stay NORMAL (cacheable): xb is the one array we want LLC-resident
#pragma unroll
    for (int ri = 0; ri < 4; ++ri) {
        const int r0 = rowBase + ri * 16 + quad * 4;
#pragma unroll
        for (int rr = 0; rr < 4; ++rr) {
            const int row = r0 + rr;
            if (row < N_NODES) {
#pragma unroll
                for (int ci = 0; ci < 4; ++ci)
                    Xb[(size_t)row * DDIM + cb + ci * 16 + lrow] = f32_to_bf16(acc[ri][ci][rr]);
            }
        }
    }
}

// ---------------- two-level CSR build ----------------
// K1: coarse histogram over NB buckets (bucket = dst>>6)
__global__ __launch_bounds__(256) void hist_coarse(const int* __restrict__ edst,
                                                   int* __restrict__ gcounts) {
    __shared__ int h[NB];
    const int tid = threadIdx.x;
    for (int i = tid; i < NB; i += 256) h[i] = 0;
    __syncthreads();
    const int lo = blockIdx.x * CHUNK;
    const int hi = lo + CHUNK;
    for (int e = lo + tid; e < hi; e += 256) atomicAdd(&h[edst[e] >> 6], 1);
    __syncthreads();
    for (int i = tid; i < NB; i += 256)
        if (h[i]) atomicAdd(&gcounts[i], h[i]);
}

// K2: scan NB bucket counts -> bbase[NB+1], bcursor copy; also off[N_NODES]=E
__global__ __launch_bounds__(256) void scan_coarse(const int* __restrict__ gcounts,
                                                   int* __restrict__ bbase,
                                                   int* __restrict__ bcursor,
                                                   int* __restrict__ off) {
    __shared__ int part[256];
    const int t = threadIdx.x;
    const int chunk = (NB + 255) / 256;  // 7
    const int lo = t * chunk;
    const int hi = min(lo + chunk, NB);
    int s = 0;
    for (int i = lo; i < hi; ++i) s += gcounts[i];
    part[t] = s;
    __syncthreads();
    for (int d = 1; d < 256; d <<= 1) {
        int a = (t >= d) ? part[t - d] : 0;
        __syncthreads();
        part[t] += a;
        __syncthreads();
    }
    int run = part[t] - s;
    for (int i = lo; i < hi; ++i) {
        bbase[i] = run;
        bcursor[i] = run;
        run += gcounts[i];
    }
    if (t == 255) {
        bbase[NB] = run;
        off[N_NODES] = run;  // == N_EDGES
    }
}

// K3: bin edges into coarse buckets. tmp is dead after refine -> nontemporal
// stores so it never occupies LLC capacity that xb needs.
__global__ __launch_bounds__(256) void bin_coarse(const int* __restrict__ esrc,
                                                  const int* __restrict__ edst,
                                                  const float* __restrict__ evals,
                                                  int* __restrict__ bcursor,
                                                  long long* __restrict__ tmp) {
    __shared__ int h[NB];
    __shared__ int sb[NB];
    const int tid = threadIdx.x;
    for (int i = tid; i < NB; i += 256) h[i] = 0;
    __syncthreads();
    const int lo = blockIdx.x * CHUNK;
    const int hi = lo + CHUNK;
    for (int e = lo + tid; e < hi; e += 256) atomicAdd(&h[edst[e] >> 6], 1);
    __syncthreads();
    for (int i = tid; i < NB; i += 256)
        sb[i] = h[i] ? atomicAdd(&bcursor[i], h[i]) : 0;
    __syncthreads();
    for (int e = lo + tid; e < hi; e += 256) {
        const int d = edst[e];
        const int b = d >> 6;
        const int p = atomicAdd(&sb[b], 1);  // LDS atomic; sb now acts as cursor
        const unsigned int lo32 = (unsigned int)(esrc[e] | ((d & 63) << 17));
        const unsigned int hi32 = (unsigned int)__float_as_int(evals[e]);
        __builtin_nontemporal_store((long long)(((unsigned long long)hi32 << 32) | lo32), &tmp[p]);
    }
}

// K4: refine within bucket: exact per-node CSR offsets + scatter inside a
// ~16KB window. tmp loads nontemporal (dead after this); srcval stores
// NORMAL (gather re-reads it next).
__global__ __launch_bounds__(256) void refine(const long long* __restrict__ tmp,
                                              const int* __restrict__ bbase,
                                              int* __restrict__ off,
                                              long long* __restrict__ srcval) {
    __shared__ int nh[64];
    __shared__ int nb[64];
    const int b = blockIdx.x;
    const int tid = threadIdx.x;
    const int base = bbase[b];
    const int cnt = bbase[b + 1] - base;
    const int n0 = b * 64;
    const int nn = min(64, N_NODES - n0);
    if (tid < 64) nh[tid] = 0;
    __syncthreads();
    for (int i = tid; i < cnt; i += 256) {
        const long long q = __builtin_nontemporal_load(&tmp[base + i]);
        atomicAdd(&nh[((int)(unsigned int)q) >> 17], 1);
    }
    __syncthreads();
    if (tid == 0) {
        int run = 0;
        for (int i = 0; i < 64; ++i) { nb[i] = run; run += nh[i]; }
    }
    __syncthreads();
    if (tid < nn) off[n0 + tid] = base + nb[tid];
    __syncthreads();  // off-write reads nb before pass-2 mutates it
    for (int i = tid; i < cnt; i += 256) {
        const long long q = __builtin_nontemporal_load(&tmp[base + i]);
        const unsigned int lo32 = (unsigned int)q;
        const int dl = (int)(lo32 >> 17);
        const int p = atomicAdd(&nb[dl], 1);
        // keep layout: lo32 = src index, hi32 = value bits
        srcval[base + p] = (long long)((q & 0xFFFFFFFF00000000ull) | (lo32 & 0x1FFFF));
    }
}

// ---------------- SpMM gather (bf16 x): one wave per destination ----------------
// srcval loads nontemporal (read once); out stores nontemporal (written once,
// never read) -- keeps the 102MB out stream + 26MB srcval stream from evicting
// the 51MB xb table out of the LLC. xb row loads stay normal/cacheable.
__global__ __launch_bounds__(256) void spmm_gather(const unsigned short* __restrict__ xb,
                                                   const int* __restrict__ off,
                                                   const long long* __restrict__ srcval,
                                                   float* __restrict__ out) {
    const int node = blockIdx.x * 4 + (threadIdx.x >> 6);
    const int lane = threadIdx.x & 63;
    const int start = off[node];
    const int end = off[node + 1];

    float4 acc = make_float4(0.f, 0.f, 0.f, 0.f);

    for (int base = start; base < end; base += 64) {
        const int cnt = min(64, end - base);
        int s_l = 0;
        float v_l = 0.f;
        if (lane < cnt) {
            const long long q = __builtin_nontemporal_load(&srcval[base + lane]);
            s_l = (int)((unsigned int)q & 0x1FFFF);
            v_l = __int_as_float((int)(q >> 32));
        }
        int j = 0;
        for (; j + 4 <= cnt; j += 4) {
            const int s0 = __shfl(s_l, j + 0);
            const int s1 = __shfl(s_l, j + 1);
            const int s2 = __shfl(s_l, j + 2);
            const int s3 = __shfl(s_l, j + 3);
            const float v0 = __shfl(v_l, j + 0);
            const float v1 = __shfl(v_l, j + 1);
            const float v2 = __shfl(v_l, j + 2);
            const float v3 = __shfl(v_l, j + 3);
            const ushort4 h0 = *(const ushort4*)&xb[(size_t)s0 * DDIM + lane * 4];
            const ushort4 h1 = *(const ushort4*)&xb[(size_t)s1 * DDIM + lane * 4];
            const ushort4 h2 = *(const ushort4*)&xb[(size_t)s2 * DDIM + lane * 4];
            const ushort4 h3 = *(const ushort4*)&xb[(size_t)s3 * DDIM + lane * 4];
            acc.x += v0 * bf16_to_f32(h0.x); acc.y += v0 * bf16_to_f32(h0.y);
            acc.z += v0 * bf16_to_f32(h0.z); acc.w += v0 * bf16_to_f32(h0.w);
            acc.x += v1 * bf16_to_f32(h1.x); acc.y += v1 * bf16_to_f32(h1.y);
            acc.z += v1 * bf16_to_f32(h1.z); acc.w += v1 * bf16_to_f32(h1.w);
            acc.x += v2 * bf16_to_f32(h2.x); acc.y += v2 * bf16_to_f32(h2.y);
            acc.z += v2 * bf16_to_f32(h2.z); acc.w += v2 * bf16_to_f32(h2.w);
            acc.x += v3 * bf16_to_f32(h3.x); acc.y += v3 * bf16_to_f32(h3.y);
            acc.z += v3 * bf16_to_f32(h3.z); acc.w += v3 * bf16_to_f32(h3.w);
        }
        for (; j < cnt; ++j) {
            const int s = __shfl(s_l, j);
            const float v = __shfl(v_l, j);
            const ushort4 h = *(const ushort4*)&xb[(size_t)s * DDIM + lane * 4];
            acc.x += v * bf16_to_f32(h.x); acc.y += v * bf16_to_f32(h.y);
            acc.z += v * bf16_to_f32(h.z); acc.w += v * bf16_to_f32(h.w);
        }
    }

    f32x4 o;
    o[0] = fmaxf(acc.x, 0.f);
    o[1] = fmaxf(acc.y, 0.f);
    o[2] = fmaxf(acc.z, 0.f);
    o[3] = fmaxf(acc.w, 0.f);
    __builtin_nontemporal_store(o, (f32x4*)&out[(size_t)node * DDIM + lane * 4]);
}

extern "C" void kernel_launch(void* const* d_in, const int* in_sizes, int n_in,
                              void* d_out, int out_size, void* d_ws, size_t ws_size,
                              hipStream_t stream) {
    const float* inputs = (const float*)d_in[0];
    const float* weight = (const float*)d_in[1];
    const int* esrc     = (const int*)d_in[2];
    const int* edst     = (const int*)d_in[3];
    const float* evals  = (const float*)d_in[4];
    float* out = (float*)d_out;

    // workspace layout (16B alignment maintained)
    unsigned short* xb = (unsigned short*)d_ws;                  // 25.6M ushort
    unsigned short* Wt = xb + (size_t)N_NODES * DDIM;            // 65536 ushort
    int* off     = (int*)(Wt + DDIM * DDIM);                     // 100001
    int* gcounts = off + N_NODES + 1;                            // NB
    int* bbase   = gcounts + NB;                                 // NB+1
    int* bcursor = bbase + NB + 1;                               // NB
    uintptr_t a  = ((uintptr_t)(bcursor + NB) + 15) & ~(uintptr_t)15;
    long long* tmp    = (long long*)a;                           // 3.2M records
    long long* srcval = tmp + N_EDGES;                           // 3.2M records

    // 1) Wt = bf16(W^T)
    prep_w<<<dim3(8, 8), 256, 0, stream>>>(weight, Wt);

    // 2) xb = bf16(inputs @ W) via MFMA
    gemm_mfma<<<(N_NODES + 63) / 64, 256, 0, stream>>>(inputs, Wt, xb);

    // 3) two-level CSR build (memset replaces the zero kernel)
    (void)hipMemsetAsync(gcounts, 0, NB * sizeof(int), stream);
    hist_coarse<<<BIN_BLK, 256, 0, stream>>>(edst, gcounts);
    scan_coarse<<<1, 256, 0, stream>>>(gcounts, bbase, bcursor, off);
    bin_coarse<<<BIN_BLK, 256, 0, stream>>>(esrc, edst, evals, bcursor, tmp);
    refine<<<NB, 256, 0, stream>>>(tmp, bbase, off, srcval);

    // 4) gather-accumulate + fused ReLU (one wave per node)
    spmm_gather<<<N_NODES / 4, 256, 0, stream>>>(xb, off, srcval, out);
}

// Round 6
// 599.797 us; speedup vs baseline: 2.4137x; 1.1001x over previous
//
#include <hip/hip_runtime.h>

#define N_NODES 100000
#define N_EDGES 3200000
#define DDIM 256
#define NB 1563          // ceil(100000/64) buckets of 64 dst nodes
#define BIN_BLK 256      // blocks for hist/bin passes; 3.2M/256 = 12500 edges/block
#define CHUNK (N_EDGES / BIN_BLK)

typedef short s16x8 __attribute__((ext_vector_type(8)));
typedef float f32x4 __attribute__((ext_vector_type(4)));
typedef float f32x2 __attribute__((ext_vector_type(2)));

__device__ __forceinline__ unsigned short f32_to_bf16(float f) {
    union { float f; unsigned int u; } c; c.f = f;
    unsigned int u = c.u;
    unsigned int r = u + 0x7fffu + ((u >> 16) & 1u);  // RNE
    return (unsigned short)(r >> 16);
}
__device__ __forceinline__ float bl16(unsigned int u) {   // low bf16 of dword -> f32
    union { unsigned int x; float f; } c; c.x = u << 16; return c.f;
}
__device__ __forceinline__ float bh16(unsigned int u) {   // high bf16 of dword -> f32
    union { unsigned int x; float f; } c; c.x = u & 0xffff0000u; return c.f;
}

// ---------------- W -> Wt (bf16, transposed to [n][k]) ----------------
__global__ __launch_bounds__(256) void prep_w(const float* __restrict__ W,
                                              unsigned short* __restrict__ Wt) {
    __shared__ float tile[32][33];
    const int tx = threadIdx.x & 31;
    const int ty = threadIdx.x >> 5;
    const int n0 = blockIdx.x * 32;
    const int k0 = blockIdx.y * 32;
    for (int i = 0; i < 32; i += 8)
        tile[ty + i][tx] = W[(size_t)(k0 + ty + i) * DDIM + n0 + tx];
    __syncthreads();
    for (int i = 0; i < 32; i += 8)
        Wt[(size_t)(n0 + ty + i) * DDIM + k0 + tx] = f32_to_bf16(tile[tx][ty + i]);
}

// ---------------- MFMA bf16 GEMM: Xb[N,256] = bf16(A) @ bf16(W) ----------------
__global__ __launch_bounds__(256) void gemm_mfma(const float* __restrict__ A,
                                                 const unsigned short* __restrict__ Wt,
                                                 unsigned short* __restrict__ Xb) {
    __shared__ unsigned short As[64][DDIM + 8];
    const int tid = threadIdx.x;
    const int rowBase = blockIdx.x * 64;

#pragma unroll
    for (int p = 0; p < 16; ++p) {
        const int flat = p * 256 + tid;
        const int row = flat >> 6;
        const int k4 = (flat & 63) * 4;
        const int gr = rowBase + row;
        float4 v = make_float4(0.f, 0.f, 0.f, 0.f);
        if (gr < N_NODES) v = *(const float4*)&A[(size_t)gr * DDIM + k4];
        ushort4 h;
        h.x = f32_to_bf16(v.x); h.y = f32_to_bf16(v.y);
        h.z = f32_to_bf16(v.z); h.w = f32_to_bf16(v.w);
        *(ushort4*)&As[row][k4] = h;
    }
    __syncthreads();

    const int wave = tid >> 6;
    const int lane = tid & 63;
    const int lrow = lane & 15;
    const int quad = lane >> 4;
    const int cb = wave * 64;

    f32x4 acc[4][4] = {};

#pragma unroll
    for (int ks = 0; ks < 8; ++ks) {
        const int k0 = ks * 32 + quad * 8;
        s16x8 a[4], b[4];
#pragma unroll
        for (int ri = 0; ri < 4; ++ri)
            a[ri] = *(const s16x8*)&As[ri * 16 + lrow][k0];
#pragma unroll
        for (int ci = 0; ci < 4; ++ci)
            b[ci] = *(const s16x8*)&Wt[(size_t)(cb + ci * 16 + lrow) * DDIM + k0];
#pragma unroll
        for (int ri = 0; ri < 4; ++ri)
#pragma unroll
            for (int ci = 0; ci < 4; ++ci)
                acc[ri][ci] = __builtin_amdgcn_mfma_f32_16x16x32_bf16(a[ri], b[ci], acc[ri][ci], 0, 0, 0);
    }

#pragma unroll
    for (int ri = 0; ri < 4; ++ri) {
        const int r0 = rowBase + ri * 16 + quad * 4;
#pragma unroll
        for (int rr = 0; rr < 4; ++rr) {
            const int row = r0 + rr;
            if (row < N_NODES) {
#pragma unroll
                for (int ci = 0; ci < 4; ++ci)
                    Xb[(size_t)row * DDIM + cb + ci * 16 + lrow] = f32_to_bf16(acc[ri][ci][rr]);
            }
        }
    }
}

// ---------------- two-level CSR build ----------------
// K1: coarse histogram over NB buckets (bucket = dst>>6)
__global__ __launch_bounds__(256) void hist_coarse(const int* __restrict__ edst,
                                                   int* __restrict__ gcounts) {
    __shared__ int h[NB];
    const int tid = threadIdx.x;
    for (int i = tid; i < NB; i += 256) h[i] = 0;
    __syncthreads();
    const int lo = blockIdx.x * CHUNK;
    const int hi = lo + CHUNK;
    for (int e = lo + tid; e < hi; e += 256) atomicAdd(&h[edst[e] >> 6], 1);
    __syncthreads();
    for (int i = tid; i < NB; i += 256)
        if (h[i]) atomicAdd(&gcounts[i], h[i]);
}

// K2: scan NB bucket counts -> bbase[NB+1], bcursor copy; also off[N_NODES]=E
__global__ __launch_bounds__(256) void scan_coarse(const int* __restrict__ gcounts,
                                                   int* __restrict__ bbase,
                                                   int* __restrict__ bcursor,
                                                   int* __restrict__ off) {
    __shared__ int part[256];
    const int t = threadIdx.x;
    const int chunk = (NB + 255) / 256;  // 7
    const int lo = t * chunk;
    const int hi = min(lo + chunk, NB);
    int s = 0;
    for (int i = lo; i < hi; ++i) s += gcounts[i];
    part[t] = s;
    __syncthreads();
    for (int d = 1; d < 256; d <<= 1) {
        int a = (t >= d) ? part[t - d] : 0;
        __syncthreads();
        part[t] += a;
        __syncthreads();
    }
    int run = part[t] - s;
    for (int i = lo; i < hi; ++i) {
        bbase[i] = run;
        bcursor[i] = run;
        run += gcounts[i];
    }
    if (t == 255) {
        bbase[NB] = run;
        off[N_NODES] = run;  // == N_EDGES
    }
}

// K3: bin edges into coarse buckets. tmp stores CACHEABLE (refine reads it
// twice right after -- NT here cost 50us in round 4).
__global__ __launch_bounds__(256) void bin_coarse(const int* __restrict__ esrc,
                                                  const int* __restrict__ edst,
                                                  const float* __restrict__ evals,
                                                  int* __restrict__ bcursor,
                                                  long long* __restrict__ tmp) {
    __shared__ int h[NB];
    __shared__ int sb[NB];
    const int tid = threadIdx.x;
    for (int i = tid; i < NB; i += 256) h[i] = 0;
    __syncthreads();
    const int lo = blockIdx.x * CHUNK;
    const int hi = lo + CHUNK;
    for (int e = lo + tid; e < hi; e += 256) atomicAdd(&h[edst[e] >> 6], 1);
    __syncthreads();
    for (int i = tid; i < NB; i += 256)
        sb[i] = h[i] ? atomicAdd(&bcursor[i], h[i]) : 0;
    __syncthreads();
    for (int e = lo + tid; e < hi; e += 256) {
        const int d = edst[e];
        const int b = d >> 6;
        const int p = atomicAdd(&sb[b], 1);  // LDS atomic; sb now acts as cursor
        const unsigned int lo32 = (unsigned int)(esrc[e] | ((d & 63) << 17));
        const unsigned int hi32 = (unsigned int)__float_as_int(evals[e]);
        tmp[p] = (long long)(((unsigned long long)hi32 << 32) | lo32);
    }
}

// K4: refine within bucket: exact per-node CSR offsets + scatter inside a
// ~16KB window (cache-resident). One workgroup per bucket.
__global__ __launch_bounds__(256) void refine(const long long* __restrict__ tmp,
                                              const int* __restrict__ bbase,
                                              int* __restrict__ off,
                                              long long* __restrict__ srcval) {
    __shared__ int nh[64];
    __shared__ int nb[64];
    const int b = blockIdx.x;
    const int tid = threadIdx.x;
    const int base = bbase[b];
    const int cnt = bbase[b + 1] - base;
    const int n0 = b * 64;
    const int nn = min(64, N_NODES - n0);
    if (tid < 64) nh[tid] = 0;
    __syncthreads();
    for (int i = tid; i < cnt; i += 256) {
        const long long q = tmp[base + i];
        atomicAdd(&nh[((int)(unsigned int)q) >> 17], 1);
    }
    __syncthreads();
    if (tid == 0) {
        int run = 0;
        for (int i = 0; i < 64; ++i) { nb[i] = run; run += nh[i]; }
    }
    __syncthreads();
    if (tid < nn) off[n0 + tid] = base + nb[tid];
    __syncthreads();  // off-write reads nb before pass-2 mutates it
    for (int i = tid; i < cnt; i += 256) {
        const long long q = tmp[base + i];
        const unsigned int lo32 = (unsigned int)q;
        const int dl = (int)(lo32 >> 17);
        const int p = atomicAdd(&nb[dl], 1);
        srcval[base + p] = (long long)((q & 0xFFFFFFFF00000000ull) | (lo32 & 0x1FFFF));
    }
}

// ---------------- SpMM gather, HALF of the dims per dispatch ----------------
// Pass covers dims [dimoff, dimoff+128). Distinct-line footprint of xb per
// pass = 25.6MB (2 of each row's 4 128B lines) -- the experiment: does a
// halved working set raise the cache hit rate / cut FETCH_SIZE?
// xbh = xb + dimoff, outh = out + dimoff. Lane covers 2 dims (uint = 2 bf16),
// wave row-request = 256B aligned. 8 edges in flight, named regs (no scratch).
#define HEDGE(q) { a0 += v##q * bl16(h##q); a1 += v##q * bh16(h##q); }

__global__ __launch_bounds__(256) void spmm_half(const unsigned short* __restrict__ xbh,
                                                 const int* __restrict__ off,
                                                 const long long* __restrict__ srcval,
                                                 float* __restrict__ outh) {
    const int node = blockIdx.x * 4 + (threadIdx.x >> 6);
    const int lane = threadIdx.x & 63;
    const int start = off[node];
    const int end = off[node + 1];

    const unsigned short* xcol = xbh + lane * 2;   // + src*DDIM
    float a0 = 0.f, a1 = 0.f;

    for (int base = start; base < end; base += 64) {
        const int cnt = min(64, end - base);
        int s_l = 0;
        float v_l = 0.f;
        if (lane < cnt) {
            const long long q = __builtin_nontemporal_load(&srcval[base + lane]);
            s_l = (int)((unsigned int)q & 0x1FFFF);
            v_l = __int_as_float((int)(q >> 32));
        }
        int j = 0;
        for (; j + 8 <= cnt; j += 8) {
            const int s0 = __shfl(s_l, j + 0);
            const int s1 = __shfl(s_l, j + 1);
            const int s2 = __shfl(s_l, j + 2);
            const int s3 = __shfl(s_l, j + 3);
            const int s4 = __shfl(s_l, j + 4);
            const int s5 = __shfl(s_l, j + 5);
            const int s6 = __shfl(s_l, j + 6);
            const int s7 = __shfl(s_l, j + 7);
            const float v0 = __shfl(v_l, j + 0);
            const float v1 = __shfl(v_l, j + 1);
            const float v2 = __shfl(v_l, j + 2);
            const float v3 = __shfl(v_l, j + 3);
            const float v4 = __shfl(v_l, j + 4);
            const float v5 = __shfl(v_l, j + 5);
            const float v6 = __shfl(v_l, j + 6);
            const float v7 = __shfl(v_l, j + 7);
            const unsigned int h0 = *(const unsigned int*)&xcol[(size_t)s0 * DDIM];
            const unsigned int h1 = *(const unsigned int*)&xcol[(size_t)s1 * DDIM];
            const unsigned int h2 = *(const unsigned int*)&xcol[(size_t)s2 * DDIM];
            const unsigned int h3 = *(const unsigned int*)&xcol[(size_t)s3 * DDIM];
            const unsigned int h4 = *(const unsigned int*)&xcol[(size_t)s4 * DDIM];
            const unsigned int h5 = *(const unsigned int*)&xcol[(size_t)s5 * DDIM];
            const unsigned int h6 = *(const unsigned int*)&xcol[(size_t)s6 * DDIM];
            const unsigned int h7 = *(const unsigned int*)&xcol[(size_t)s7 * DDIM];
            HEDGE(0) HEDGE(1) HEDGE(2) HEDGE(3)
            HEDGE(4) HEDGE(5) HEDGE(6) HEDGE(7)
        }
        for (; j < cnt; ++j) {
            const int s = __shfl(s_l, j);
            const float v = __shfl(v_l, j);
            const unsigned int h = *(const unsigned int*)&xcol[(size_t)s * DDIM];
            a0 += v * bl16(h); a1 += v * bh16(h);
        }
    }

    f32x2 o;
    o[0] = fmaxf(a0, 0.f);
    o[1] = fmaxf(a1, 0.f);
    __builtin_nontemporal_store(o, (f32x2*)&outh[(size_t)node * DDIM + lane * 2]);
}
#undef HEDGE

extern "C" void kernel_launch(void* const* d_in, const int* in_sizes, int n_in,
                              void* d_out, int out_size, void* d_ws, size_t ws_size,
                              hipStream_t stream) {
    const float* inputs = (const float*)d_in[0];
    const float* weight = (const float*)d_in[1];
    const int* esrc     = (const int*)d_in[2];
    const int* edst     = (const int*)d_in[3];
    const float* evals  = (const float*)d_in[4];
    float* out = (float*)d_out;

    // workspace layout (16B alignment maintained)
    unsigned short* xb = (unsigned short*)d_ws;                  // 25.6M ushort
    unsigned short* Wt = xb + (size_t)N_NODES * DDIM;            // 65536 ushort
    int* off     = (int*)(Wt + DDIM * DDIM);                     // 100001
    int* gcounts = off + N_NODES + 1;                            // NB
    int* bbase   = gcounts + NB;                                 // NB+1
    int* bcursor = bbase + NB + 1;                               // NB
    uintptr_t a  = ((uintptr_t)(bcursor + NB) + 15) & ~(uintptr_t)15;
    long long* tmp    = (long long*)a;                           // 3.2M records
    long long* srcval = tmp + N_EDGES;                           // 3.2M records

    // 1) Wt = bf16(W^T)
    prep_w<<<dim3(8, 8), 256, 0, stream>>>(weight, Wt);

    // 2) xb = bf16(inputs @ W) via MFMA
    gemm_mfma<<<(N_NODES + 63) / 64, 256, 0, stream>>>(inputs, Wt, xb);

    // 3) two-level CSR build
    (void)hipMemsetAsync(gcounts, 0, NB * sizeof(int), stream);
    hist_coarse<<<BIN_BLK, 256, 0, stream>>>(edst, gcounts);
    scan_coarse<<<1, 256, 0, stream>>>(gcounts, bbase, bcursor, off);
    bin_coarse<<<BIN_BLK, 256, 0, stream>>>(esrc, edst, evals, bcursor, tmp);
    refine<<<NB, 256, 0, stream>>>(tmp, bbase, off, srcval);

    // 4) gather in two half-dim passes (temporal phase separation -> per-pass
    //    xb line footprint 25.6MB). Fused ReLU in each pass.
    spmm_half<<<N_NODES / 4, 256, 0, stream>>>(xb,       off, srcval, out);
    spmm_half<<<N_NODES / 4, 256, 0, stream>>>(xb + 128, off, srcval, out + 128);
}

// Round 7
// 561.344 us; speedup vs baseline: 2.5790x; 1.0685x over previous
//
#include <hip/hip_runtime.h>

#define N_NODES 100000
#define N_EDGES 3200000
#define DDIM 256
#define NB 1563          // ceil(100000/64) buckets of 64 dst nodes
#define BIN_BLK 256      // blocks for hist/bin passes; 3.2M/256 = 12500 edges/block
#define CHUNK (N_EDGES / BIN_BLK)
#define TB 1024          // threads/block for hist/bin (16 waves -> latency hiding)

typedef short s16x8 __attribute__((ext_vector_type(8)));
typedef float f32x4 __attribute__((ext_vector_type(4)));
typedef float f32x2 __attribute__((ext_vector_type(2)));

__device__ __forceinline__ unsigned short f32_to_bf16(float f) {
    union { float f; unsigned int u; } c; c.f = f;
    unsigned int u = c.u;
    unsigned int r = u + 0x7fffu + ((u >> 16) & 1u);  // RNE
    return (unsigned short)(r >> 16);
}
__device__ __forceinline__ float bl16(unsigned int u) {   // low bf16 of dword -> f32
    union { unsigned int x; float f; } c; c.x = u << 16; return c.f;
}
__device__ __forceinline__ float bh16(unsigned int u) {   // high bf16 of dword -> f32
    union { unsigned int x; float f; } c; c.x = u & 0xffff0000u; return c.f;
}

// ---------------- W -> Wt (bf16, transposed to [n][k]) ----------------
__global__ __launch_bounds__(256) void prep_w(const float* __restrict__ W,
                                              unsigned short* __restrict__ Wt) {
    __shared__ float tile[32][33];
    const int tx = threadIdx.x & 31;
    const int ty = threadIdx.x >> 5;
    const int n0 = blockIdx.x * 32;
    const int k0 = blockIdx.y * 32;
    for (int i = 0; i < 32; i += 8)
        tile[ty + i][tx] = W[(size_t)(k0 + ty + i) * DDIM + n0 + tx];
    __syncthreads();
    for (int i = 0; i < 32; i += 8)
        Wt[(size_t)(n0 + ty + i) * DDIM + k0 + tx] = f32_to_bf16(tile[tx][ty + i]);
}

// ---------------- MFMA bf16 GEMM: Xb[N,256] = bf16(A) @ bf16(W) ----------------
__global__ __launch_bounds__(256) void gemm_mfma(const float* __restrict__ A,
                                                 const unsigned short* __restrict__ Wt,
                                                 unsigned short* __restrict__ Xb) {
    __shared__ unsigned short As[64][DDIM + 8];
    const int tid = threadIdx.x;
    const int rowBase = blockIdx.x * 64;

#pragma unroll
    for (int p = 0; p < 16; ++p) {
        const int flat = p * 256 + tid;
        const int row = flat >> 6;
        const int k4 = (flat & 63) * 4;
        const int gr = rowBase + row;
        float4 v = make_float4(0.f, 0.f, 0.f, 0.f);
        if (gr < N_NODES) v = *(const float4*)&A[(size_t)gr * DDIM + k4];
        ushort4 h;
        h.x = f32_to_bf16(v.x); h.y = f32_to_bf16(v.y);
        h.z = f32_to_bf16(v.z); h.w = f32_to_bf16(v.w);
        *(ushort4*)&As[row][k4] = h;
    }
    __syncthreads();

    const int wave = tid >> 6;
    const int lane = tid & 63;
    const int lrow = lane & 15;
    const int quad = lane >> 4;
    const int cb = wave * 64;

    f32x4 acc[4][4] = {};

#pragma unroll
    for (int ks = 0; ks < 8; ++ks) {
        const int k0 = ks * 32 + quad * 8;
        s16x8 a[4], b[4];
#pragma unroll
        for (int ri = 0; ri < 4; ++ri)
            a[ri] = *(const s16x8*)&As[ri * 16 + lrow][k0];
#pragma unroll
        for (int ci = 0; ci < 4; ++ci)
            b[ci] = *(const s16x8*)&Wt[(size_t)(cb + ci * 16 + lrow) * DDIM + k0];
#pragma unroll
        for (int ri = 0; ri < 4; ++ri)
#pragma unroll
            for (int ci = 0; ci < 4; ++ci)
                acc[ri][ci] = __builtin_amdgcn_mfma_f32_16x16x32_bf16(a[ri], b[ci], acc[ri][ci], 0, 0, 0);
    }

#pragma unroll
    for (int ri = 0; ri < 4; ++ri) {
        const int r0 = rowBase + ri * 16 + quad * 4;
#pragma unroll
        for (int rr = 0; rr < 4; ++rr) {
            const int row = r0 + rr;
            if (row < N_NODES) {
#pragma unroll
                for (int ci = 0; ci < 4; ++ci)
                    Xb[(size_t)row * DDIM + cb + ci * 16 + lrow] = f32_to_bf16(acc[ri][ci][rr]);
            }
        }
    }
}

// ---------------- two-level CSR build ----------------
// K1: coarse histogram over NB buckets (bucket = dst>>6). 1024 threads/block:
// same 256-block / CHUNK=12500 decomposition, 4x the waves for latency hiding.
__global__ __launch_bounds__(TB) void hist_coarse(const int* __restrict__ edst,
                                                  int* __restrict__ gcounts) {
    __shared__ int h[NB];
    const int tid = threadIdx.x;
    for (int i = tid; i < NB; i += TB) h[i] = 0;
    __syncthreads();
    const int lo = blockIdx.x * CHUNK;
    const int hi = lo + CHUNK;
    for (int e = lo + tid; e < hi; e += TB) atomicAdd(&h[edst[e] >> 6], 1);
    __syncthreads();
    for (int i = tid; i < NB; i += TB)
        if (h[i]) atomicAdd(&gcounts[i], h[i]);
}

// K2: scan NB bucket counts -> bbase[NB+1], bcursor copy; also off[N_NODES]=E
__global__ __launch_bounds__(256) void scan_coarse(const int* __restrict__ gcounts,
                                                   int* __restrict__ bbase,
                                                   int* __restrict__ bcursor,
                                                   int* __restrict__ off) {
    __shared__ int part[256];
    const int t = threadIdx.x;
    const int chunk = (NB + 255) / 256;  // 7
    const int lo = t * chunk;
    const int hi = min(lo + chunk, NB);
    int s = 0;
    for (int i = lo; i < hi; ++i) s += gcounts[i];
    part[t] = s;
    __syncthreads();
    for (int d = 1; d < 256; d <<= 1) {
        int a = (t >= d) ? part[t - d] : 0;
        __syncthreads();
        part[t] += a;
        __syncthreads();
    }
    int run = part[t] - s;
    for (int i = lo; i < hi; ++i) {
        bbase[i] = run;
        bcursor[i] = run;
        run += gcounts[i];
    }
    if (t == 255) {
        bbase[NB] = run;
        off[N_NODES] = run;  // == N_EDGES
    }
}

// K3: bin edges into coarse buckets. 1024 threads/block (was 256: 10%
// occupancy, 1.2% VALUBusy -- pure latency crawl). Span size per bucket
// (~8 records) unchanged, so write density is preserved.
__global__ __launch_bounds__(TB) void bin_coarse(const int* __restrict__ esrc,
                                                 const int* __restrict__ edst,
                                                 const float* __restrict__ evals,
                                                 int* __restrict__ bcursor,
                                                 long long* __restrict__ tmp) {
    __shared__ int h[NB];
    __shared__ int sb[NB];
    const int tid = threadIdx.x;
    for (int i = tid; i < NB; i += TB) h[i] = 0;
    __syncthreads();
    const int lo = blockIdx.x * CHUNK;
    const int hi = lo + CHUNK;
    for (int e = lo + tid; e < hi; e += TB) atomicAdd(&h[edst[e] >> 6], 1);
    __syncthreads();
    for (int i = tid; i < NB; i += TB)
        sb[i] = h[i] ? atomicAdd(&bcursor[i], h[i]) : 0;
    __syncthreads();
    for (int e = lo + tid; e < hi; e += TB) {
        const int d = edst[e];
        const int b = d >> 6;
        const int p = atomicAdd(&sb[b], 1);  // LDS atomic; sb now acts as cursor
        const unsigned int lo32 = (unsigned int)(esrc[e] | ((d & 63) << 17));
        const unsigned int hi32 = (unsigned int)__float_as_int(evals[e]);
        tmp[p] = (long long)(((unsigned long long)hi32 << 32) | lo32);
    }
}

// K4: refine within bucket: exact per-node CSR offsets + scatter inside a
// ~16KB window (cache-resident). One workgroup per bucket.
__global__ __launch_bounds__(256) void refine(const long long* __restrict__ tmp,
                                              const int* __restrict__ bbase,
                                              int* __restrict__ off,
                                              long long* __restrict__ srcval) {
    __shared__ int nh[64];
    __shared__ int nb[64];
    const int b = blockIdx.x;
    const int tid = threadIdx.x;
    const int base = bbase[b];
    const int cnt = bbase[b + 1] - base;
    const int n0 = b * 64;
    const int nn = min(64, N_NODES - n0);
    if (tid < 64) nh[tid] = 0;
    __syncthreads();
    for (int i = tid; i < cnt; i += 256) {
        const long long q = tmp[base + i];
        atomicAdd(&nh[((int)(unsigned int)q) >> 17], 1);
    }
    __syncthreads();
    if (tid == 0) {
        int run = 0;
        for (int i = 0; i < 64; ++i) { nb[i] = run; run += nh[i]; }
    }
    __syncthreads();
    if (tid < nn) off[n0 + tid] = base + nb[tid];
    __syncthreads();  // off-write reads nb before pass-2 mutates it
    for (int i = tid; i < cnt; i += 256) {
        const long long q = tmp[base + i];
        const unsigned int lo32 = (unsigned int)q;
        const int dl = (int)(lo32 >> 17);
        const int p = atomicAdd(&nb[dl], 1);
        srcval[base + p] = (long long)((q & 0xFFFFFFFF00000000ull) | (lo32 & 0x1FFFF));
    }
}

// ---------------- SpMM gather, HALF of the dims per dispatch ----------------
// Pass covers dims [dimoff, dimoff+128). Two passes; combined ~219us at
// ~7.4 TB/s delivered row bandwidth (structural ceiling for this pattern).
#define HEDGE(q) { a0 += v##q * bl16(h##q); a1 += v##q * bh16(h##q); }

__global__ __launch_bounds__(256) void spmm_half(const unsigned short* __restrict__ xbh,
                                                 const int* __restrict__ off,
                                                 const long long* __restrict__ srcval,
                                                 float* __restrict__ outh) {
    const int node = blockIdx.x * 4 + (threadIdx.x >> 6);
    const int lane = threadIdx.x & 63;
    const int start = off[node];
    const int end = off[node + 1];

    const unsigned short* xcol = xbh + lane * 2;   // + src*DDIM
    float a0 = 0.f, a1 = 0.f;

    for (int base = start; base < end; base += 64) {
        const int cnt = min(64, end - base);
        int s_l = 0;
        float v_l = 0.f;
        if (lane < cnt) {
            const long long q = __builtin_nontemporal_load(&srcval[base + lane]);
            s_l = (int)((unsigned int)q & 0x1FFFF);
            v_l = __int_as_float((int)(q >> 32));
        }
        int j = 0;
        for (; j + 8 <= cnt; j += 8) {
            const int s0 = __shfl(s_l, j + 0);
            const int s1 = __shfl(s_l, j + 1);
            const int s2 = __shfl(s_l, j + 2);
            const int s3 = __shfl(s_l, j + 3);
            const int s4 = __shfl(s_l, j + 4);
            const int s5 = __shfl(s_l, j + 5);
            const int s6 = __shfl(s_l, j + 6);
            const int s7 = __shfl(s_l, j + 7);
            const float v0 = __shfl(v_l, j + 0);
            const float v1 = __shfl(v_l, j + 1);
            const float v2 = __shfl(v_l, j + 2);
            const float v3 = __shfl(v_l, j + 3);
            const float v4 = __shfl(v_l, j + 4);
            const float v5 = __shfl(v_l, j + 5);
            const float v6 = __shfl(v_l, j + 6);
            const float v7 = __shfl(v_l, j + 7);
            const unsigned int h0 = *(const unsigned int*)&xcol[(size_t)s0 * DDIM];
            const unsigned int h1 = *(const unsigned int*)&xcol[(size_t)s1 * DDIM];
            const unsigned int h2 = *(const unsigned int*)&xcol[(size_t)s2 * DDIM];
            const unsigned int h3 = *(const unsigned int*)&xcol[(size_t)s3 * DDIM];
            const unsigned int h4 = *(const unsigned int*)&xcol[(size_t)s4 * DDIM];
            const unsigned int h5 = *(const unsigned int*)&xcol[(size_t)s5 * DDIM];
            const unsigned int h6 = *(const unsigned int*)&xcol[(size_t)s6 * DDIM];
            const unsigned int h7 = *(const unsigned int*)&xcol[(size_t)s7 * DDIM];
            HEDGE(0) HEDGE(1) HEDGE(2) HEDGE(3)
            HEDGE(4) HEDGE(5) HEDGE(6) HEDGE(7)
        }
        for (; j < cnt; ++j) {
            const int s = __shfl(s_l, j);
            const float v = __shfl(v_l, j);
            const unsigned int h = *(const unsigned int*)&xcol[(size_t)s * DDIM];
            a0 += v * bl16(h); a1 += v * bh16(h);
        }
    }

    f32x2 o;
    o[0] = fmaxf(a0, 0.f);
    o[1] = fmaxf(a1, 0.f);
    __builtin_nontemporal_store(o, (f32x2*)&outh[(size_t)node * DDIM + lane * 2]);
}
#undef HEDGE

extern "C" void kernel_launch(void* const* d_in, const int* in_sizes, int n_in,
                              void* d_out, int out_size, void* d_ws, size_t ws_size,
                              hipStream_t stream) {
    const float* inputs = (const float*)d_in[0];
    const float* weight = (const float*)d_in[1];
    const int* esrc     = (const int*)d_in[2];
    const int* edst     = (const int*)d_in[3];
    const float* evals  = (const float*)d_in[4];
    float* out = (float*)d_out;

    // workspace layout (16B alignment maintained)
    unsigned short* xb = (unsigned short*)d_ws;                  // 25.6M ushort
    unsigned short* Wt = xb + (size_t)N_NODES * DDIM;            // 65536 ushort
    int* off     = (int*)(Wt + DDIM * DDIM);                     // 100001
    int* gcounts = off + N_NODES + 1;                            // NB
    int* bbase   = gcounts + NB;                                 // NB+1
    int* bcursor = bbase + NB + 1;                               // NB
    uintptr_t a  = ((uintptr_t)(bcursor + NB) + 15) & ~(uintptr_t)15;
    long long* tmp    = (long long*)a;                           // 3.2M records
    long long* srcval = tmp + N_EDGES;                           // 3.2M records

    // 1) Wt = bf16(W^T)
    prep_w<<<dim3(8, 8), 256, 0, stream>>>(weight, Wt);

    // 2) xb = bf16(inputs @ W) via MFMA
    gemm_mfma<<<(N_NODES + 63) / 64, 256, 0, stream>>>(inputs, Wt, xb);

    // 3) two-level CSR build (hist/bin widened to 1024 threads)
    (void)hipMemsetAsync(gcounts, 0, NB * sizeof(int), stream);
    hist_coarse<<<BIN_BLK, TB, 0, stream>>>(edst, gcounts);
    scan_coarse<<<1, 256, 0, stream>>>(gcounts, bbase, bcursor, off);
    bin_coarse<<<BIN_BLK, TB, 0, stream>>>(esrc, edst, evals, bcursor, tmp);
    refine<<<NB, 256, 0, stream>>>(tmp, bbase, off, srcval);

    // 4) gather in two half-dim passes + fused ReLU
    spmm_half<<<N_NODES / 4, 256, 0, stream>>>(xb,       off, srcval, out);
    spmm_half<<<N_NODES / 4, 256, 0, stream>>>(xb + 128, off, srcval, out + 128);
}

// Round 8
// 548.336 us; speedup vs baseline: 2.6402x; 1.0237x over previous
//
#include <hip/hip_runtime.h>

#define N_NODES 100000
#define N_EDGES 3200000
#define DDIM 256
#define NB 1563          // ceil(100000/64) buckets of 64 dst nodes
#define BIN_BLK 256      // blocks for hist/bin passes; 3.2M/256 = 12500 edges/block
#define CHUNK (N_EDGES / BIN_BLK)
#define TB 1024          // threads/block for hist/bin/refine (16 waves -> latency hiding)

typedef short s16x8 __attribute__((ext_vector_type(8)));
typedef float f32x4 __attribute__((ext_vector_type(4)));
typedef float f32x2 __attribute__((ext_vector_type(2)));

__device__ __forceinline__ unsigned short f32_to_bf16(float f) {
    union { float f; unsigned int u; } c; c.f = f;
    unsigned int u = c.u;
    unsigned int r = u + 0x7fffu + ((u >> 16) & 1u);  // RNE
    return (unsigned short)(r >> 16);
}
__device__ __forceinline__ float bl16(unsigned int u) {   // low bf16 of dword -> f32
    union { unsigned int x; float f; } c; c.x = u << 16; return c.f;
}
__device__ __forceinline__ float bh16(unsigned int u) {   // high bf16 of dword -> f32
    union { unsigned int x; float f; } c; c.x = u & 0xffff0000u; return c.f;
}

// ---------------- W -> Wt (bf16, transposed to [n][k]) ----------------
__global__ __launch_bounds__(256) void prep_w(const float* __restrict__ W,
                                              unsigned short* __restrict__ Wt) {
    __shared__ float tile[32][33];
    const int tx = threadIdx.x & 31;
    const int ty = threadIdx.x >> 5;
    const int n0 = blockIdx.x * 32;
    const int k0 = blockIdx.y * 32;
    for (int i = 0; i < 32; i += 8)
        tile[ty + i][tx] = W[(size_t)(k0 + ty + i) * DDIM + n0 + tx];
    __syncthreads();
    for (int i = 0; i < 32; i += 8)
        Wt[(size_t)(n0 + ty + i) * DDIM + k0 + tx] = f32_to_bf16(tile[tx][ty + i]);
}

// ---------------- MFMA bf16 GEMM: Xb[N,256] = bf16(A) @ bf16(W) ----------------
// Epilogue: acc -> LDS (bf16, reusing As) -> coalesced ushort8 global stores.
// (Previous version: 64 scalar 2-B global stores per wave = store-issue tail.)
__global__ __launch_bounds__(256) void gemm_mfma(const float* __restrict__ A,
                                                 const unsigned short* __restrict__ Wt,
                                                 unsigned short* __restrict__ Xb) {
    __shared__ unsigned short As[64][DDIM + 8];
    const int tid = threadIdx.x;
    const int rowBase = blockIdx.x * 64;

#pragma unroll
    for (int p = 0; p < 16; ++p) {
        const int flat = p * 256 + tid;
        const int row = flat >> 6;
        const int k4 = (flat & 63) * 4;
        const int gr = rowBase + row;
        float4 v = make_float4(0.f, 0.f, 0.f, 0.f);
        if (gr < N_NODES) v = *(const float4*)&A[(size_t)gr * DDIM + k4];
        ushort4 h;
        h.x = f32_to_bf16(v.x); h.y = f32_to_bf16(v.y);
        h.z = f32_to_bf16(v.z); h.w = f32_to_bf16(v.w);
        *(ushort4*)&As[row][k4] = h;
    }
    __syncthreads();

    const int wave = tid >> 6;
    const int lane = tid & 63;
    const int lrow = lane & 15;
    const int quad = lane >> 4;
    const int cb = wave * 64;

    f32x4 acc[4][4] = {};

#pragma unroll
    for (int ks = 0; ks < 8; ++ks) {
        const int k0 = ks * 32 + quad * 8;
        s16x8 a[4], b[4];
#pragma unroll
        for (int ri = 0; ri < 4; ++ri)
            a[ri] = *(const s16x8*)&As[ri * 16 + lrow][k0];
#pragma unroll
        for (int ci = 0; ci < 4; ++ci)
            b[ci] = *(const s16x8*)&Wt[(size_t)(cb + ci * 16 + lrow) * DDIM + k0];
#pragma unroll
        for (int ri = 0; ri < 4; ++ri)
#pragma unroll
            for (int ci = 0; ci < 4; ++ci)
                acc[ri][ci] = __builtin_amdgcn_mfma_f32_16x16x32_bf16(a[ri], b[ci], acc[ri][ci], 0, 0, 0);
    }

    __syncthreads();   // done reading As as A-tile; reuse it as C-tile
#pragma unroll
    for (int ri = 0; ri < 4; ++ri)
#pragma unroll
        for (int rr = 0; rr < 4; ++rr)
#pragma unroll
            for (int ci = 0; ci < 4; ++ci)
                As[ri * 16 + quad * 4 + rr][cb + ci * 16 + lrow] =
                    f32_to_bf16(acc[ri][ci][rr]);
    __syncthreads();

    // stream out: 64 rows x 256 cols bf16 = 32KB, 16B chunks, fully coalesced
#pragma unroll
    for (int it = 0; it < 8; ++it) {
        const int flat = it * 256 + tid;     // 2048 chunks of 8 ushorts
        const int row  = flat >> 5;          // 32 chunks per row
        const int c8   = (flat & 31) * 8;
        const int grow = rowBase + row;
        if (grow < N_NODES)
            *(s16x8*)&Xb[(size_t)grow * DDIM + c8] = *(const s16x8*)&As[row][c8];
    }
}

// ---------------- two-level CSR build ----------------
// K1: coarse histogram over NB buckets (bucket = dst>>6)
__global__ __launch_bounds__(TB) void hist_coarse(const int* __restrict__ edst,
                                                  int* __restrict__ gcounts) {
    __shared__ int h[NB];
    const int tid = threadIdx.x;
    for (int i = tid; i < NB; i += TB) h[i] = 0;
    __syncthreads();
    const int lo = blockIdx.x * CHUNK;
    const int hi = lo + CHUNK;
    for (int e = lo + tid; e < hi; e += TB) atomicAdd(&h[edst[e] >> 6], 1);
    __syncthreads();
    for (int i = tid; i < NB; i += TB)
        if (h[i]) atomicAdd(&gcounts[i], h[i]);
}

// K2: scan NB bucket counts -> bbase[NB+1], bcursor copy; also off[N_NODES]=E
__global__ __launch_bounds__(256) void scan_coarse(const int* __restrict__ gcounts,
                                                   int* __restrict__ bbase,
                                                   int* __restrict__ bcursor,
                                                   int* __restrict__ off) {
    __shared__ int part[256];
    const int t = threadIdx.x;
    const int chunk = (NB + 255) / 256;  // 7
    const int lo = t * chunk;
    const int hi = min(lo + chunk, NB);
    int s = 0;
    for (int i = lo; i < hi; ++i) s += gcounts[i];
    part[t] = s;
    __syncthreads();
    for (int d = 1; d < 256; d <<= 1) {
        int a = (t >= d) ? part[t - d] : 0;
        __syncthreads();
        part[t] += a;
        __syncthreads();
    }
    int run = part[t] - s;
    for (int i = lo; i < hi; ++i) {
        bbase[i] = run;
        bcursor[i] = run;
        run += gcounts[i];
    }
    if (t == 255) {
        bbase[NB] = run;
        off[N_NODES] = run;  // == N_EDGES
    }
}

// K3: bin edges into coarse buckets (1024 threads)
__global__ __launch_bounds__(TB) void bin_coarse(const int* __restrict__ esrc,
                                                 const int* __restrict__ edst,
                                                 const float* __restrict__ evals,
                                                 int* __restrict__ bcursor,
                                                 long long* __restrict__ tmp) {
    __shared__ int h[NB];
    __shared__ int sb[NB];
    const int tid = threadIdx.x;
    for (int i = tid; i < NB; i += TB) h[i] = 0;
    __syncthreads();
    const int lo = blockIdx.x * CHUNK;
    const int hi = lo + CHUNK;
    for (int e = lo + tid; e < hi; e += TB) atomicAdd(&h[edst[e] >> 6], 1);
    __syncthreads();
    for (int i = tid; i < NB; i += TB)
        sb[i] = h[i] ? atomicAdd(&bcursor[i], h[i]) : 0;
    __syncthreads();
    for (int e = lo + tid; e < hi; e += TB) {
        const int d = edst[e];
        const int b = d >> 6;
        const int p = atomicAdd(&sb[b], 1);  // LDS atomic; sb now acts as cursor
        const unsigned int lo32 = (unsigned int)(esrc[e] | ((d & 63) << 17));
        const unsigned int hi32 = (unsigned int)__float_as_int(evals[e]);
        tmp[p] = (long long)(((unsigned long long)hi32 << 32) | lo32);
    }
}

// K4: refine within bucket (now 1024 threads): exact per-node CSR offsets +
// scatter inside a ~16KB cache-resident window. One workgroup per bucket.
__global__ __launch_bounds__(TB) void refine(const long long* __restrict__ tmp,
                                             const int* __restrict__ bbase,
                                             int* __restrict__ off,
                                             long long* __restrict__ srcval) {
    __shared__ int nh[64];
    __shared__ int nb[64];
    const int b = blockIdx.x;
    const int tid = threadIdx.x;
    const int base = bbase[b];
    const int cnt = bbase[b + 1] - base;
    const int n0 = b * 64;
    const int nn = min(64, N_NODES - n0);
    if (tid < 64) nh[tid] = 0;
    __syncthreads();
    for (int i = tid; i < cnt; i += TB) {
        const long long q = tmp[base + i];
        atomicAdd(&nh[((int)(unsigned int)q) >> 17], 1);
    }
    __syncthreads();
    if (tid == 0) {
        int run = 0;
        for (int i = 0; i < 64; ++i) { nb[i] = run; run += nh[i]; }
    }
    __syncthreads();
    if (tid < nn) off[n0 + tid] = base + nb[tid];
    __syncthreads();  // off-write reads nb before pass-2 mutates it
    for (int i = tid; i < cnt; i += TB) {
        const long long q = tmp[base + i];
        const unsigned int lo32 = (unsigned int)q;
        const int dl = (int)(lo32 >> 17);
        const int p = atomicAdd(&nb[dl], 1);
        srcval[base + p] = (long long)((q & 0xFFFFFFFF00000000ull) | (lo32 & 0x1FFFF));
    }
}

// ---------------- SpMM gather, half-dims per blockIdx.y ----------------
// blockIdx.y in {0,1} selects dims [y*128, y*128+128). Single dispatch.
#define HEDGE(q) { a0 += v##q * bl16(h##q); a1 += v##q * bh16(h##q); }

__global__ __launch_bounds__(256) void spmm_half(const unsigned short* __restrict__ xb,
                                                 const int* __restrict__ off,
                                                 const long long* __restrict__ srcval,
                                                 float* __restrict__ out) {
    const int node = blockIdx.x * 4 + (threadIdx.x >> 6);
    const int lane = threadIdx.x & 63;
    const int dimoff = blockIdx.y << 7;
    const int start = off[node];
    const int end = off[node + 1];

    const unsigned short* xcol = xb + dimoff + lane * 2;   // + src*DDIM
    float a0 = 0.f, a1 = 0.f;

    for (int base = start; base < end; base += 64) {
        const int cnt = min(64, end - base);
        int s_l = 0;
        float v_l = 0.f;
        if (lane < cnt) {
            const long long q = __builtin_nontemporal_load(&srcval[base + lane]);
            s_l = (int)((unsigned int)q & 0x1FFFF);
            v_l = __int_as_float((int)(q >> 32));
        }
        int j = 0;
        for (; j + 8 <= cnt; j += 8) {
            const int s0 = __shfl(s_l, j + 0);
            const int s1 = __shfl(s_l, j + 1);
            const int s2 = __shfl(s_l, j + 2);
            const int s3 = __shfl(s_l, j + 3);
            const int s4 = __shfl(s_l, j + 4);
            const int s5 = __shfl(s_l, j + 5);
            const int s6 = __shfl(s_l, j + 6);
            const int s7 = __shfl(s_l, j + 7);
            const float v0 = __shfl(v_l, j + 0);
            const float v1 = __shfl(v_l, j + 1);
            const float v2 = __shfl(v_l, j + 2);
            const float v3 = __shfl(v_l, j + 3);
            const float v4 = __shfl(v_l, j + 4);
            const float v5 = __shfl(v_l, j + 5);
            const float v6 = __shfl(v_l, j + 6);
            const float v7 = __shfl(v_l, j + 7);
            const unsigned int h0 = *(const unsigned int*)&xcol[(size_t)s0 * DDIM];
            const unsigned int h1 = *(const unsigned int*)&xcol[(size_t)s1 * DDIM];
            const unsigned int h2 = *(const unsigned int*)&xcol[(size_t)s2 * DDIM];
            const unsigned int h3 = *(const unsigned int*)&xcol[(size_t)s3 * DDIM];
            const unsigned int h4 = *(const unsigned int*)&xcol[(size_t)s4 * DDIM];
            const unsigned int h5 = *(const unsigned int*)&xcol[(size_t)s5 * DDIM];
            const unsigned int h6 = *(const unsigned int*)&xcol[(size_t)s6 * DDIM];
            const unsigned int h7 = *(const unsigned int*)&xcol[(size_t)s7 * DDIM];
            HEDGE(0) HEDGE(1) HEDGE(2) HEDGE(3)
            HEDGE(4) HEDGE(5) HEDGE(6) HEDGE(7)
        }
        for (; j < cnt; ++j) {
            const int s = __shfl(s_l, j);
            const float v = __shfl(v_l, j);
            const unsigned int h = *(const unsigned int*)&xcol[(size_t)s * DDIM];
            a0 += v * bl16(h); a1 += v * bh16(h);
        }
    }

    f32x2 o;
    o[0] = fmaxf(a0, 0.f);
    o[1] = fmaxf(a1, 0.f);
    __builtin_nontemporal_store(o, (f32x2*)&out[(size_t)node * DDIM + dimoff + lane * 2]);
}
#undef HEDGE

extern "C" void kernel_launch(void* const* d_in, const int* in_sizes, int n_in,
                              void* d_out, int out_size, void* d_ws, size_t ws_size,
                              hipStream_t stream) {
    const float* inputs = (const float*)d_in[0];
    const float* weight = (const float*)d_in[1];
    const int* esrc     = (const int*)d_in[2];
    const int* edst     = (const int*)d_in[3];
    const float* evals  = (const float*)d_in[4];
    float* out = (float*)d_out;

    // workspace layout (16B alignment maintained)
    unsigned short* xb = (unsigned short*)d_ws;                  // 25.6M ushort
    unsigned short* Wt = xb + (size_t)N_NODES * DDIM;            // 65536 ushort
    int* off     = (int*)(Wt + DDIM * DDIM);                     // 100001
    int* gcounts = off + N_NODES + 1;                            // NB
    int* bbase   = gcounts + NB;                                 // NB+1
    int* bcursor = bbase + NB + 1;                               // NB
    uintptr_t a  = ((uintptr_t)(bcursor + NB) + 15) & ~(uintptr_t)15;
    long long* tmp    = (long long*)a;                           // 3.2M records
    long long* srcval = tmp + N_EDGES;                           // 3.2M records

    // 1) Wt = bf16(W^T)
    prep_w<<<dim3(8, 8), 256, 0, stream>>>(weight, Wt);

    // 2) xb = bf16(inputs @ W) via MFMA, coalesced epilogue
    gemm_mfma<<<(N_NODES + 63) / 64, 256, 0, stream>>>(inputs, Wt, xb);

    // 3) two-level CSR build (all wide kernels)
    (void)hipMemsetAsync(gcounts, 0, NB * sizeof(int), stream);
    hist_coarse<<<BIN_BLK, TB, 0, stream>>>(edst, gcounts);
    scan_coarse<<<1, 256, 0, stream>>>(gcounts, bbase, bcursor, off);
    bin_coarse<<<BIN_BLK, TB, 0, stream>>>(esrc, edst, evals, bcursor, tmp);
    refine<<<NB, TB, 0, stream>>>(tmp, bbase, off, srcval);

    // 4) gather in one dispatch, two half-dim planes via blockIdx.y
    spmm_half<<<dim3(N_NODES / 4, 2), 256, 0, stream>>>(xb, off, srcval, out);
}